// Round 17
// baseline (648.745 us; speedup 1.0000x reference)
//
#include <hip/hip_runtime.h>

#define BATCH 1024
#define NNODE 92
#define FIN   1024
#define FOUT  512

typedef float    f32x4 __attribute__((ext_vector_type(4)));
typedef _Float16 half8 __attribute__((ext_vector_type(8)));
typedef _Float16 half4 __attribute__((ext_vector_type(4)));
typedef unsigned int uint4v __attribute__((ext_vector_type(4)));

__device__ __forceinline__ float lrelu(float x) { return fmaxf(x, 0.2f * x); }

#define BAR_LGKM() do {                                                        \
    asm volatile("s_waitcnt lgkmcnt(0)" ::: "memory");                         \
    __builtin_amdgcn_sched_barrier(0);                                         \
    __builtin_amdgcn_s_barrier();                                              \
  } while (0)

// ---------------------------------------------------------------------------
// prep: WT[n][k] = f16(W[k][n]); ATp[j][k] = f16(A[k][j]) padded [96][104];
//       wa1[k] = sum_o W[k][o]*a[o], wa2[k] = sum_o W[k][o]*a[512+o]
// ---------------------------------------------------------------------------
__global__ __launch_bounds__(256) void prep_kernel(
    const float* __restrict__ W, const float* __restrict__ Am,
    const float* __restrict__ av,
    _Float16* __restrict__ WT, _Float16* __restrict__ ATp,
    float* __restrict__ wa1, float* __restrict__ wa2) {
  int bid = blockIdx.x, t = threadIdx.x;
  if (bid < 64) {
    int n0 = bid * 8;
    for (int it = 0; it < 4; ++it) {
      int k = it * 256 + t;
      const f32x4* src = (const f32x4*)(W + (size_t)k * FOUT + n0);
      f32x4 v0 = src[0], v1 = src[1];
      #pragma unroll
      for (int c = 0; c < 4; ++c) {
        WT[(size_t)(n0 + c) * FIN + k]     = (_Float16)v0[c];
        WT[(size_t)(n0 + 4 + c) * FIN + k] = (_Float16)v1[c];
      }
    }
  } else if (bid < 68) {
    int j0 = (bid - 64) * 24;
    for (int idx = t; idx < 24 * 104; idx += 256) {
      int jr = idx / 104, k = idx - jr * 104;
      int j = j0 + jr;
      float v = (j < NNODE && k < NNODE) ? Am[k * NNODE + j] : 0.f;
      ATp[j * 104 + k] = (_Float16)v;
    }
  } else {
    int k = (bid - 68) * 256 + t;
    const f32x4* wr = (const f32x4*)(W + (size_t)k * FOUT);
    const f32x4* a1 = (const f32x4*)(av);
    const f32x4* a2 = (const f32x4*)(av + FOUT);
    float s1 = 0.f, s2 = 0.f;
    for (int o = 0; o < FOUT / 4; ++o) {
      f32x4 wv = wr[o], x1 = a1[o], x2 = a2[o];
      #pragma unroll
      for (int c = 0; c < 4; ++c) {
        s1 = fmaf(wv[c], x1[c], s1);
        s2 = fmaf(wv[c], x2[c], s2);
      }
    }
    wa1[k] = s1; wa2[k] = s2;
  }
}

// ---------------------------------------------------------------------------
// FUSED half-split: 2048 blocks x 512 thr; block = (batch, C-half).
//  XCD pairing: half=(bid>>3)&1, batch=(bid>>4)*8+(bid&7) -- the two halves
//  of a batch land on the same XCD so X[b] is read from HBM once.
//  GEMM: acc[6][2] (C = half*256 + w*32 + ...), 16 phases BK=64, R16's
//    phase-ahead B preload; per-phase GEMV (threads<384) accumulates
//    Wh1/Wh2 from staged X against wa1/wa2 (LDS).
//  NO whT: PV B-fragments built in-register from packed acc via __shfl
//    (dual-shfl + select keeps array indices static).
//  QK A-fragment built in-register from w1s/w2s (e0 never materialized);
//  at_ overlays dead xs; e0a holds only att. LDS 45.3 KB -> 2 blocks/CU.
// LDS (bytes): xs0 0 | xs1 12288 | at_ overlays 0 post-GEMM |
//   att 24576 (pre-use: wa1l 24576, wa2l 28672, red 32768) |
//   w1s 44544 | w2s 44928 | total 45312.
// ---------------------------------------------------------------------------
__global__ __launch_bounds__(512, 4) void fused_kernel(
    const float* __restrict__ X, const _Float16* __restrict__ WT,
    const _Float16* __restrict__ ATp, const int* __restrict__ adj,
    const float* __restrict__ wa1g, const float* __restrict__ wa2g,
    const float* __restrict__ bias, float* __restrict__ out) {
  extern __shared__ char smem[];
  _Float16* xs0 = (_Float16*)smem;                  // [96][64] swz
  _Float16* xs1 = (_Float16*)(smem + 12288);
  _Float16* at_ = (_Float16*)smem;                  // overlays xs post-GEMM
  _Float16* att = (_Float16*)(smem + 24576);        // [96][104]
  float* wa1l = (float*)(smem + 24576);             // [1024] (pre-att)
  float* wa2l = (float*)(smem + 28672);             // [1024] (pre-att)
  float* red  = (float*)(smem + 32768);             // [96][8] (pre-att)
  float* w1s  = (float*)(smem + 44544);             // [96]
  float* w2s  = (float*)(smem + 44928);             // [96]

  int t = threadIdx.x, l = t & 63, w = t >> 6;
  unsigned bid = blockIdx.x;
  int half = (bid >> 3) & 1;
  int b = (int)((bid >> 4) * 8 + (bid & 7));
  const float* Xb = X + (size_t)b * NNODE * FIN;
  int g = l >> 4, c16 = l & 15;

  // X staging maps (R16): idx = c*512+t, row = idx>>4, kq = idx&15
  int xrow[3], xwoff[3];
  bool xok[3];
  #pragma unroll
  for (int c = 0; c < 3; ++c) {
    int idx = c * 512 + t;
    int row = idx >> 4, kq = idx & 15;
    xrow[c] = (row < 92) ? row : 91;
    xok[c] = (row < 92);
    xwoff[c] = row * 128 + (((kq >> 1) ^ (row & 7)) << 4) + (kq & 1) * 8;
  }

  // B fragment base: n = half*256 + w*32 + ni*16 + (l&15)
  const _Float16* WTb = WT + (size_t)(half * 256 + w * 32 + c16) * FIN + g * 8;

  // GEMV map: threads 0..383: row = t>>2, kq4 = t&3 (16 k per phase)
  int grow = t >> 2, kq4 = t & 3;
  bool gvok = (t < 384);

  f32x4 zz = {0.f, 0.f, 0.f, 0.f};
  f32x4 acc[6][2];
  #pragma unroll
  for (int mi = 0; mi < 6; ++mi)
    #pragma unroll
    for (int ni = 0; ni < 2; ++ni) acc[mi][ni] = zz;

  float s1 = 0.f, s2 = 0.f;
  f32x4 xvA[3], xvB[3];
  half8 bf0[2], bf1[2], bf2[2], bf3[2];

#define F_XISSUE(XV, KT) do {                                                  \
    int ktc_ = (KT) > 15 ? 15 : (KT);                                          \
    _Pragma("unroll")                                                          \
    for (int c = 0; c < 3; ++c) {                                              \
      int idx_ = c * 512 + t;                                                  \
      (XV)[c] = *(const f32x4*)(Xb + (size_t)xrow[c] * FIN + ktc_ * 64 +       \
                                (idx_ & 15) * 4);                              \
    }                                                                          \
  } while (0)

#define F_XCONV(BUF, XV) do {                                                  \
    _Pragma("unroll")                                                          \
    for (int c = 0; c < 3; ++c) {                                              \
      half4 h;                                                                 \
      if (xok[c]) {                                                            \
        h[0] = (_Float16)(XV)[c][0]; h[1] = (_Float16)(XV)[c][1];              \
        h[2] = (_Float16)(XV)[c][2]; h[3] = (_Float16)(XV)[c][3];              \
      } else {                                                                 \
        h[0] = (_Float16)0.f; h[1] = (_Float16)0.f;                            \
        h[2] = (_Float16)0.f; h[3] = (_Float16)0.f;                            \
      }                                                                        \
      *(half4*)((char*)(BUF) + xwoff[c]) = h;                                  \
    }                                                                          \
  } while (0)

#define F_BFLOAD(DST, KT, S) do {                                              \
    int ktc_ = (KT) > 15 ? 15 : (KT);                                          \
    _Pragma("unroll")                                                          \
    for (int ni = 0; ni < 2; ++ni)                                             \
      (DST)[ni] = *(const half8*)(WTb + (size_t)(ni * 16) * FIN +              \
                                  ktc_ * 64 + (S) * 32);                       \
  } while (0)

#define F_MFMA(XSBUF, BF, S) do {                                              \
    half8 af[6];                                                               \
    _Pragma("unroll")                                                          \
    for (int mi = 0; mi < 6; ++mi) {                                           \
      int row_ = mi * 16 + c16;                                                \
      int slot_ = (((S) * 4 + g) ^ (row_ & 7));                                \
      af[mi] = *(const half8*)((const char*)(XSBUF) + row_ * 128 +             \
                               slot_ * 16);                                    \
    }                                                                          \
    _Pragma("unroll")                                                          \
    for (int mi = 0; mi < 6; ++mi)                                             \
      _Pragma("unroll")                                                        \
      for (int ni = 0; ni < 2; ++ni)                                           \
        acc[mi][ni] = __builtin_amdgcn_mfma_f32_16x16x32_f16(                  \
            af[mi], (BF)[ni], acc[mi][ni], 0, 0, 0);                           \
  } while (0)

#define F_GEMV(CUR, KT) do {                                                   \
    if (gvok) {                                                                \
      int k0_ = (KT) * 64 + kq4 * 16;                                          \
      f32x4 w1c[4], w2c[4];                                                    \
      _Pragma("unroll")                                                        \
      for (int q = 0; q < 4; ++q) {                                            \
        w1c[q] = *(const f32x4*)(wa1l + k0_ + q * 4);                          \
        w2c[q] = *(const f32x4*)(wa2l + k0_ + q * 4);                          \
      }                                                                        \
      _Pragma("unroll")                                                        \
      for (int q = 0; q < 4; ++q) {                                            \
        int kq_ = kq4 * 4 + q;                                                 \
        half4 xv4 = *(const half4*)((const char*)(CUR) + grow * 128 +          \
                    (((kq_ >> 1) ^ (grow & 7)) << 4) + (kq_ & 1) * 8);         \
        _Pragma("unroll")                                                      \
        for (int cc = 0; cc < 4; ++cc) {                                       \
          float x_ = (float)xv4[cc];                                           \
          s1 = fmaf(x_, w1c[q][cc], s1);                                       \
          s2 = fmaf(x_, w2c[q][cc], s2);                                       \
        }                                                                      \
      }                                                                        \
    }                                                                          \
  } while (0)

#define F_PHASE(KT, XN, XP, CUR, NXT, BC0, BC1, BN0, BN1) do {                 \
    F_BFLOAD(BN0, (KT) + 1, 0);                                                \
    F_BFLOAD(BN1, (KT) + 1, 1);                                                \
    F_XISSUE(XN, (KT) + 2);                                                    \
    F_MFMA(CUR, BC0, 0);                                                       \
    F_MFMA(CUR, BC1, 1);                                                       \
    F_GEMV(CUR, KT);                                                           \
    F_XCONV(NXT, XP);                                                          \
    BAR_LGKM();                                                                \
  } while (0)

  // prologue: X(0) staged; wa12 staged; bf tile-0 loaded; X(1) in flight
  F_XISSUE(xvA, 0);
  F_XCONV(xs0, xvA);              // waits X(0) only
  {
    f32x4 wv1a = *(const f32x4*)(wa1g + t * 4 + (t & 1) * 0);  // t*4 linear? no
  }
  // stage wa1l/wa2l: 512 threads x 2 elems each array
  wa1l[t] = wa1g[t]; wa1l[512 + t] = wa1g[512 + t];
  wa2l[t] = wa2g[t]; wa2l[512 + t] = wa2g[512 + t];
  F_BFLOAD(bf0, 0, 0);
  F_BFLOAD(bf1, 0, 1);
  F_XISSUE(xvA, 1);
  BAR_LGKM();

  #pragma unroll 1
  for (int kt = 0; kt < 16; kt += 2) {
    F_PHASE(kt + 0, xvB, xvA, xs0, xs1, bf0, bf1, bf2, bf3);
    F_PHASE(kt + 1, xvA, xvB, xs1, xs0, bf2, bf3, bf0, bf1);
  }

  // ---- adj prefetch (waves 0-5) + at_ global loads issued early
  int adjv[4][6];
  if (w < 6) {
    #pragma unroll
    for (int r = 0; r < 4; ++r) {
      int i = 16 * w + g * 4 + r;
      int ic = (i < 92) ? i : 91;
      #pragma unroll
      for (int ni = 0; ni < 6; ++ni) {
        int j = ni * 16 + c16;
        int jc = (j < 92) ? j : 91;
        adjv[r][ni] = adj[((size_t)b * NNODE + ic) * NNODE + jc];
      }
    }
  }
  half8 atv[3];
  bool aok2 = (t < 224);
  atv[0] = *(const half8*)(ATp + (size_t)t * 8);
  atv[1] = *(const half8*)(ATp + (size_t)(512 + t) * 8);
  if (aok2) atv[2] = *(const half8*)(ATp + (size_t)(1024 + t) * 8);

  // ---- pack acc -> f16 pairs (Wh held in registers; replaces whT)
  unsigned phl[6][2], phh[6][2];
  #pragma unroll
  for (int mi = 0; mi < 6; ++mi)
    #pragma unroll
    for (int ni = 0; ni < 2; ++ni) {
      half4 h;
      h[0] = (_Float16)acc[mi][ni][0]; h[1] = (_Float16)acc[mi][ni][1];
      h[2] = (_Float16)acc[mi][ni][2]; h[3] = (_Float16)acc[mi][ni][3];
      unsigned long long u = *(const unsigned long long*)&h;
      phl[mi][ni] = (unsigned)u;
      phh[mi][ni] = (unsigned)(u >> 32);
    }

  // ---- GEMV partials -> red, at_ LDS writes
  if (gvok) {
    red[grow * 8 + kq4 * 2]     = s1;
    red[grow * 8 + kq4 * 2 + 1] = s2;
  }
  *(half8*)(at_ + (size_t)t * 8) = atv[0];
  *(half8*)(at_ + (size_t)(512 + t) * 8) = atv[1];
  if (aok2) *(half8*)(at_ + (size_t)(1024 + t) * 8) = atv[2];
  __syncthreads();

  if (t < 96) {
    float r1 = 0.f, r2 = 0.f;
    #pragma unroll
    for (int q = 0; q < 4; ++q) {
      r1 += red[t * 8 + q * 2];
      r2 += red[t * 8 + q * 2 + 1];
    }
    w1s[t] = r1;    // rows 92..95: zeroed X rows -> 0
    w2s[t] = r2;
  }
  __syncthreads();

  // ---- QK (waves 0-5): A-frag built in-register from w1s/w2s; B from at_
  if (w < 6) {
    f32x4 ez = {0.f, 0.f, 0.f, 0.f};
    f32x4 eacc[6];
    #pragma unroll
    for (int ni = 0; ni < 6; ++ni) eacc[ni] = ez;
    float w1i = w1s[16 * w + c16];
    #pragma unroll
    for (int ks = 0; ks < 3; ++ks) {
      int k0 = ks * 32 + g * 8;
      half8 ea;
      #pragma unroll
      for (int j = 0; j < 8; ++j)
        ea[j] = (_Float16)lrelu(w1i + w2s[k0 + j]);
      #pragma unroll
      for (int ni = 0; ni < 6; ++ni) {
        half8 bt = *(const half8*)((const char*)at_ +
                   (16 * ni + c16) * 208 + ks * 64 + g * 16);
        eacc[ni] = __builtin_amdgcn_mfma_f32_16x16x32_f16(ea, bt, eacc[ni], 0, 0, 0);
      }
    }
    float attv[4][6];
    #pragma unroll
    for (int r = 0; r < 4; ++r) {
      int i = 16 * w + g * 4 + r;
      float s[6]; float m = -3.0e38f;
      #pragma unroll
      for (int ni = 0; ni < 6; ++ni) {
        int j = ni * 16 + c16;
        float e = lrelu(eacc[ni][r]);
        float sv = -3.0e38f;
        if (i < 92 && j < 92)
          sv = (adjv[r][ni] > 0) ? e : -9.0e15f;
        s[ni] = sv;
        m = fmaxf(m, sv);
      }
      #pragma unroll
      for (int mm = 1; mm < 16; mm <<= 1) m = fmaxf(m, __shfl_xor(m, mm));
      float sum = 0.f; float p[6];
      #pragma unroll
      for (int ni = 0; ni < 6; ++ni) {
        int j = ni * 16 + c16;
        p[ni] = (i < 92 && j < 92) ? __expf(s[ni] - m) : 0.f;
        sum += p[ni];
      }
      #pragma unroll
      for (int mm = 1; mm < 16; mm <<= 1) sum += __shfl_xor(sum, mm);
      float rs = (i < 92) ? (1.0f / sum) : 0.f;
      #pragma unroll
      for (int ni = 0; ni < 6; ++ni) attv[r][ni] = p[ni] * rs;
    }
    #pragma unroll
    for (int r = 0; r < 4; ++r) {
      int i = 16 * w + g * 4 + r;
      #pragma unroll
      for (int ni = 0; ni < 6; ++ni)
        att[i * 104 + ni * 16 + c16] = (_Float16)attv[r][ni];
    }
  }
  BAR_LGKM();   // att visible

  // ---- PV: out = att @ Wh + bias; B-frags from registers via dual shfl
  {
    f32x4 pz = {0.f, 0.f, 0.f, 0.f};
    f32x4 pacc[6][2];
    #pragma unroll
    for (int mi = 0; mi < 6; ++mi)
      #pragma unroll
      for (int ni = 0; ni < 2; ++ni) pacc[mi][ni] = pz;
    int sA = ((g & 1) * 2) * 16 + c16;
    int sB = sA + 16;
    bool hi = (g >> 1) != 0;
    #pragma unroll
    for (int ks = 0; ks < 3; ++ks) {
      half8 af[6];
      #pragma unroll
      for (int mi = 0; mi < 6; ++mi)
        af[mi] = *(const half8*)((const char*)att +
                 (16 * mi + c16) * 208 + ks * 64 + g * 16);
      #pragma unroll
      for (int ni = 0; ni < 2; ++ni) {
        unsigned a0 = __shfl(phl[2 * ks][ni], sA, 64);
        unsigned b0 = __shfl(phl[2 * ks + 1][ni], sA, 64);
        unsigned a1 = __shfl(phh[2 * ks][ni], sA, 64);
        unsigned b1 = __shfl(phh[2 * ks + 1][ni], sA, 64);
        unsigned a2 = __shfl(phl[2 * ks][ni], sB, 64);
        unsigned b2 = __shfl(phl[2 * ks + 1][ni], sB, 64);
        unsigned a3 = __shfl(phh[2 * ks][ni], sB, 64);
        unsigned b3 = __shfl(phh[2 * ks + 1][ni], sB, 64);
        uint4v uv;
        uv[0] = hi ? b0 : a0;
        uv[1] = hi ? b1 : a1;
        uv[2] = hi ? b2 : a2;
        uv[3] = hi ? b3 : a3;
        half8 bfv = *(const half8*)&uv;
        #pragma unroll
        for (int mi = 0; mi < 6; ++mi)
          pacc[mi][ni] = __builtin_amdgcn_mfma_f32_16x16x32_f16(
              af[mi], bfv, pacc[mi][ni], 0, 0, 0);
      }
    }
    #pragma unroll
    for (int ni = 0; ni < 2; ++ni) {
      int fcol = half * 256 + w * 32 + ni * 16 + c16;
      float bv = bias[fcol];
      #pragma unroll
      for (int mi = 0; mi < 6; ++mi)
        #pragma unroll
        for (int r = 0; r < 4; ++r) {
          int i = 16 * mi + g * 4 + r;
          if (i < 92)
            out[((size_t)b * NNODE + i) * FOUT + fcol] = pacc[mi][ni][r] + bv;
        }
    }
  }
}

// ---------------------------------------------------------------------------
extern "C" void kernel_launch(void* const* d_in, const int* in_sizes, int n_in,
                              void* d_out, int out_size, void* d_ws, size_t ws_size,
                              hipStream_t stream) {
  (void)in_sizes; (void)n_in; (void)out_size; (void)ws_size;
  const float* X    = (const float*)d_in[0];
  const int*   adj  = (const int*)d_in[1];
  const float* W    = (const float*)d_in[2];
  const float* av   = (const float*)d_in[3];
  const float* Am   = (const float*)d_in[4];
  const float* bias = (const float*)d_in[5];
  float* out = (float*)d_out;
  char* ws = (char*)d_ws;

  _Float16* WT  = (_Float16*)(ws);              // 1,048,576 B
  _Float16* ATp = (_Float16*)(ws + 1048576);    //    19,968 B
  float* wa1 = (float*)(ws + 1068544);          //     4,096 B
  float* wa2 = (float*)(ws + 1072640);          //     4,096 B

  prep_kernel<<<72, 256, 0, stream>>>(W, Am, av, WT, ATp, wa1, wa2);
  hipFuncSetAttribute((const void*)fused_kernel,
                      hipFuncAttributeMaxDynamicSharedMemorySize, 45312);
  fused_kernel<<<2048, 512, 45312, stream>>>(X, WT, ATp, adj, wa1, wa2,
                                             bias, out);
}

// Round 18
// 244.962 us; speedup vs baseline: 2.6483x; 2.6483x over previous
//
#include <hip/hip_runtime.h>

#define BATCH 1024
#define NNODE 92
#define FIN   1024
#define FOUT  512

typedef float    f32x4 __attribute__((ext_vector_type(4)));
typedef _Float16 half8 __attribute__((ext_vector_type(8)));
typedef _Float16 half4 __attribute__((ext_vector_type(4)));

__device__ __forceinline__ float lrelu(float x) { return fmaxf(x, 0.2f * x); }

#define BAR_LGKM() do {                                                        \
    asm volatile("s_waitcnt lgkmcnt(0)" ::: "memory");                         \
    __builtin_amdgcn_sched_barrier(0);                                         \
    __builtin_amdgcn_s_barrier();                                              \
  } while (0)

// ---------------------------------------------------------------------------
// prep: WT[n][k] = f16(W[k][n]);  ATp[j][k] = f16(A[k][j]) padded [96][104]
// ---------------------------------------------------------------------------
__global__ __launch_bounds__(256) void prep_kernel(
    const float* __restrict__ W, const float* __restrict__ Am,
    _Float16* __restrict__ WT, _Float16* __restrict__ ATp) {
  int bid = blockIdx.x, t = threadIdx.x;
  if (bid < 64) {
    int n0 = bid * 8;
    for (int it = 0; it < 4; ++it) {
      int k = it * 256 + t;
      const f32x4* src = (const f32x4*)(W + (size_t)k * FOUT + n0);
      f32x4 v0 = src[0], v1 = src[1];
      #pragma unroll
      for (int c = 0; c < 4; ++c) {
        WT[(size_t)(n0 + c) * FIN + k]     = (_Float16)v0[c];
        WT[(size_t)(n0 + 4 + c) * FIN + k] = (_Float16)v1[c];
      }
    }
  } else {
    int j0 = (bid - 64) * 24;
    for (int idx = t; idx < 24 * 104; idx += 256) {
      int jr = idx / 104, k = idx - jr * 104;
      int j = j0 + jr;
      float v = (j < NNODE && k < NNODE) ? Am[k * NNODE + j] : 0.f;
      ATp[j * 104 + k] = (_Float16)v;
    }
  }
}

// ---------------------------------------------------------------------------
// FUSED, 512 threads (8 waves), one block per batch, 1 block/CU.
//  R16 (best: 241 us) + bias prefetched into regs with adj/at_ (tail loads
//  issued early, consumed ~10 us later in the PV epilogue).
//   (1) B-fragments preloaded a FULL phase ahead (4 reg sets, rotated).
//   (2) adj prefetched into regs right after the GEMM loop (clamped).
//   (3) at_ stage split: global loads issued with adj, LDS writes late.
//  GEMM: Wh[b] = X[b] @ W into LDS whT[512][104]; 16 phases BK=64; wave
//    tile 96m x 64n (acc[6][4]); X dbuf-staged; B global->reg from L2 WT.
//  Attention: fused Wh1/Wh2, at_ overlays dead xs, e0 -> QK (waves 0-5) ->
//    softmax -> att -> PV (2 passes x 32 cols) -> out.
// LDS map (bytes): whT 0 | xs0 106496 | xs1 118784 | at_ overlays 106496 |
//   e0a 131072 | red 151040 | w1s 157184 | w2s 157568 | total 157952.
// ---------------------------------------------------------------------------
__global__ __launch_bounds__(512, 2) void fused_kernel(
    const float* __restrict__ X, const _Float16* __restrict__ WT,
    const _Float16* __restrict__ ATp, const int* __restrict__ adj,
    const float* __restrict__ av, const float* __restrict__ bias,
    float* __restrict__ out) {
  extern __shared__ char smem[];
  _Float16* whT = (_Float16*)smem;                  // [512][104]
  _Float16* xs0 = (_Float16*)(smem + 106496);       // [96][64] swz
  _Float16* xs1 = (_Float16*)(smem + 118784);
  _Float16* at_ = (_Float16*)(smem + 106496);       // overlays xs after GEMM
  _Float16* e0a = (_Float16*)(smem + 131072);       // [96][104]
  float* red = (float*)(smem + 151040);             // [96][16]
  float* w1s = (float*)(smem + 157184);             // [96]
  float* w2s = (float*)(smem + 157568);             // [96]

  int t = threadIdx.x, l = t & 63, w = t >> 6;
  int b = blockIdx.x;
  const float* Xb = X + (size_t)b * NNODE * FIN;

  // ---- X staging maps: idx = c*512+t, row = idx>>4 (0..95), kq = idx&15
  int xrow[3], xwoff[3];
  bool xok[3];
  #pragma unroll
  for (int c = 0; c < 3; ++c) {
    int idx = c * 512 + t;
    int row = idx >> 4, kq = idx & 15;
    xrow[c] = (row < 92) ? row : 91;
    xok[c] = (row < 92);
    xwoff[c] = row * 128 + (((kq >> 1) ^ (row & 7)) << 4) + (kq & 1) * 8;
  }

  // ---- B direct-from-global fragment base
  const _Float16* WTb = WT + (size_t)(w * 64 + (l & 15)) * FIN + (l >> 4) * 8;

  f32x4 zz = {0.f, 0.f, 0.f, 0.f};
  f32x4 acc[6][4];
  #pragma unroll
  for (int mi = 0; mi < 6; ++mi)
    #pragma unroll
    for (int ni = 0; ni < 4; ++ni) acc[mi][ni] = zz;

  f32x4 xvA[3], xvB[3];
  half8 bf0[4], bf1[4], bf2[4], bf3[4];

#define F_XISSUE(XV, KT) do {                                                  \
    int ktc_ = (KT) > 15 ? 15 : (KT);                                          \
    _Pragma("unroll")                                                          \
    for (int c = 0; c < 3; ++c) {                                              \
      int idx_ = c * 512 + t;                                                  \
      (XV)[c] = *(const f32x4*)(Xb + (size_t)xrow[c] * FIN + ktc_ * 64 +       \
                                (idx_ & 15) * 4);                              \
    }                                                                          \
  } while (0)

#define F_XCONV(BUF, XV) do {                                                  \
    _Pragma("unroll")                                                          \
    for (int c = 0; c < 3; ++c) {                                              \
      half4 h;                                                                 \
      if (xok[c]) {                                                            \
        h[0] = (_Float16)(XV)[c][0]; h[1] = (_Float16)(XV)[c][1];              \
        h[2] = (_Float16)(XV)[c][2]; h[3] = (_Float16)(XV)[c][3];              \
      } else {                                                                 \
        h[0] = (_Float16)0.f; h[1] = (_Float16)0.f;                            \
        h[2] = (_Float16)0.f; h[3] = (_Float16)0.f;                            \
      }                                                                        \
      *(half4*)((char*)(BUF) + xwoff[c]) = h;                                  \
    }                                                                          \
  } while (0)

#define F_BFLOAD(DST, KT, S) do {                                              \
    int ktc_ = (KT) > 15 ? 15 : (KT);                                          \
    _Pragma("unroll")                                                          \
    for (int ni = 0; ni < 4; ++ni)                                             \
      (DST)[ni] = *(const half8*)(WTb + (size_t)(ni * 16) * FIN +              \
                                  ktc_ * 64 + (S) * 32);                       \
  } while (0)

#define F_MFMA(XSBUF, BF, S) do {                                              \
    half8 af[6];                                                               \
    _Pragma("unroll")                                                          \
    for (int mi = 0; mi < 6; ++mi) {                                           \
      int row_ = mi * 16 + (l & 15);                                           \
      int slot_ = (((S) * 4 + (l >> 4)) ^ (row_ & 7));                         \
      af[mi] = *(const half8*)((const char*)(XSBUF) + row_ * 128 +             \
                               slot_ * 16);                                    \
    }                                                                          \
    _Pragma("unroll")                                                          \
    for (int mi = 0; mi < 6; ++mi)                                             \
      _Pragma("unroll")                                                        \
      for (int ni = 0; ni < 4; ++ni)                                           \
        acc[mi][ni] = __builtin_amdgcn_mfma_f32_16x16x32_f16(                  \
            af[mi], (BF)[ni], acc[mi][ni], 0, 0, 0);                           \
  } while (0)

// phase KT: preload NEXT phase's B (both halves), then X(KT+2); MFMA uses
// the CURRENT sets loaded a full phase ago (fully resident -- no vmem wait).
#define F_PHASE(KT, XN, XP, CUR, NXT, BC0, BC1, BN0, BN1) do {                 \
    F_BFLOAD(BN0, (KT) + 1, 0);                                                \
    F_BFLOAD(BN1, (KT) + 1, 1);                                                \
    F_XISSUE(XN, (KT) + 2);                                                    \
    F_MFMA(CUR, BC0, 0);                                                       \
    F_MFMA(CUR, BC1, 1);                                                       \
    F_XCONV(NXT, XP);                                                          \
    BAR_LGKM();                                                                \
  } while (0)

  // prologue: X(0) staged; bf0/bf1 = tile 0; X(1) in flight
  F_XISSUE(xvA, 0);
  F_XCONV(xs0, xvA);              // waits X(0) only
  F_BFLOAD(bf0, 0, 0);
  F_BFLOAD(bf1, 0, 1);
  F_XISSUE(xvA, 1);
  BAR_LGKM();

  #pragma unroll 1
  for (int kt = 0; kt < 16; kt += 2) {
    F_PHASE(kt + 0, xvB, xvA, xs0, xs1, bf0, bf1, bf2, bf3);
    F_PHASE(kt + 1, xvA, xvB, xs1, xs0, bf2, bf3, bf0, bf1);
  }

  // ---- adj prefetch into regs (consumed by softmax much later)
  int adjv[4][6];
  if (w < 6) {
    #pragma unroll
    for (int r = 0; r < 4; ++r) {
      int i = 16 * w + (l >> 4) * 4 + r;
      int ic = (i < 92) ? i : 91;
      #pragma unroll
      for (int ni = 0; ni < 6; ++ni) {
        int j = ni * 16 + (l & 15);
        int jc = (j < 92) ? j : 91;
        adjv[r][ni] = adj[((size_t)b * NNODE + ic) * NNODE + jc];
      }
    }
  }
  // ---- bias prefetch into regs (consumed by PV epilogue much later)
  float bvp[2][2];
  #pragma unroll
  for (int pp = 0; pp < 2; ++pp)
    #pragma unroll
    for (int ni = 0; ni < 2; ++ni)
      bvp[pp][ni] = bias[pp * 256 + w * 32 + ni * 16 + (l & 15)];
  // ---- at_ stage: ISSUE loads now, write to LDS later
  half8 atv[3];
  bool aok2 = (t < 224);
  atv[0] = *(const half8*)(ATp + (size_t)t * 8);
  atv[1] = *(const half8*)(ATp + (size_t)(512 + t) * 8);
  if (aok2) atv[2] = *(const half8*)(ATp + (size_t)(1024 + t) * 8);

  // ---- whT write: acc -> whT[C][m] (half4, m-quads aligned)
  #pragma unroll
  for (int mi = 0; mi < 6; ++mi) {
    int m4 = mi * 16 + (l >> 4) * 4;
    #pragma unroll
    for (int ni = 0; ni < 4; ++ni) {
      int C = w * 64 + ni * 16 + (l & 15);
      half4 h;
      h[0] = (_Float16)acc[mi][ni][0]; h[1] = (_Float16)acc[mi][ni][1];
      h[2] = (_Float16)acc[mi][ni][2]; h[3] = (_Float16)acc[mi][ni][3];
      *(half4*)((char*)whT + C * 208 + m4 * 2) = h;
    }
  }

  // ---- Wh1/Wh2 = acc . a : per-lane over owned C, shfl-reduce, red[96][16]
  {
    float aC1[4], aC2[4];
    #pragma unroll
    for (int ni = 0; ni < 4; ++ni) {
      int C = w * 64 + ni * 16 + (l & 15);
      aC1[ni] = av[C];
      aC2[ni] = av[FOUT + C];
    }
    float p1[6][4], p2[6][4];
    #pragma unroll
    for (int mi = 0; mi < 6; ++mi)
      #pragma unroll
      for (int r = 0; r < 4; ++r) {
        float s1 = 0.f, s2 = 0.f;
        #pragma unroll
        for (int ni = 0; ni < 4; ++ni) {
          s1 = fmaf(acc[mi][ni][r], aC1[ni], s1);
          s2 = fmaf(acc[mi][ni][r], aC2[ni], s2);
        }
        p1[mi][r] = s1; p2[mi][r] = s2;
      }
    #pragma unroll
    for (int mm = 1; mm < 16; mm <<= 1)
      #pragma unroll
      for (int mi = 0; mi < 6; ++mi)
        #pragma unroll
        for (int r = 0; r < 4; ++r) {
          p1[mi][r] += __shfl_xor(p1[mi][r], mm);
          p2[mi][r] += __shfl_xor(p2[mi][r], mm);
        }
    if ((l & 15) == 0) {
      #pragma unroll
      for (int mi = 0; mi < 6; ++mi)
        #pragma unroll
        for (int r = 0; r < 4; ++r) {
          int m = mi * 16 + (l >> 4) * 4 + r;
          red[m * 16 + w * 2]     = p1[mi][r];
          red[m * 16 + w * 2 + 1] = p2[mi][r];
        }
    }
  }
  // ---- at_ LDS writes (loads have been in flight across whT+reduction)
  *(half8*)(at_ + (size_t)t * 8) = atv[0];
  *(half8*)(at_ + (size_t)(512 + t) * 8) = atv[1];
  if (aok2) *(half8*)(at_ + (size_t)(1024 + t) * 8) = atv[2];
  __syncthreads();

  if (t < 96) {
    float s1 = 0.f, s2 = 0.f;
    #pragma unroll
    for (int q = 0; q < 8; ++q) {
      s1 += red[t * 16 + q * 2];
      s2 += red[t * 16 + q * 2 + 1];
    }
    w1s[t] = s1;    // rows 92..95 are 0 (zeroed X rows)
    w2s[t] = s2;
  }
  __syncthreads();

  // ---- e0[i][k] = lrelu(Wh1[i]+Wh2[k]), zero-padded [96][104]
  for (int idx = t; idx < 96 * 128; idx += 512) {
    int i = idx >> 7, k = idx & 127;
    if (k < 104) {
      float v = (i < 92 && k < 92) ? lrelu(w1s[i] + w2s[k]) : 0.f;
      e0a[i * 104 + k] = (_Float16)v;
    }
  }
  BAR_LGKM();

  // ---- QK: e = lrelu(e0 @ A), mask (adjv regs), softmax; att -> e0a
  if (w < 6) {
    f32x4 ez = {0.f, 0.f, 0.f, 0.f};
    f32x4 eacc[6];
    #pragma unroll
    for (int ni = 0; ni < 6; ++ni) eacc[ni] = ez;
    #pragma unroll
    for (int ks = 0; ks < 3; ++ks) {
      half8 ea = *(const half8*)((const char*)e0a +
                 (16 * w + (l & 15)) * 208 + ks * 64 + (l >> 4) * 16);
      #pragma unroll
      for (int ni = 0; ni < 6; ++ni) {
        half8 bt = *(const half8*)((const char*)at_ +
                   (16 * ni + (l & 15)) * 208 + ks * 64 + (l >> 4) * 16);
        eacc[ni] = __builtin_amdgcn_mfma_f32_16x16x32_f16(ea, bt, eacc[ni], 0, 0, 0);
      }
    }
    float attv[4][6];
    #pragma unroll
    for (int r = 0; r < 4; ++r) {
      int i = 16 * w + (l >> 4) * 4 + r;
      float s[6]; float m = -3.0e38f;
      #pragma unroll
      for (int ni = 0; ni < 6; ++ni) {
        int j = ni * 16 + (l & 15);
        float e = lrelu(eacc[ni][r]);
        float sv = -3.0e38f;
        if (i < 92 && j < 92)
          sv = (adjv[r][ni] > 0) ? e : -9.0e15f;
        s[ni] = sv;
        m = fmaxf(m, sv);
      }
      #pragma unroll
      for (int mm = 1; mm < 16; mm <<= 1) m = fmaxf(m, __shfl_xor(m, mm));
      float sum = 0.f; float p[6];
      #pragma unroll
      for (int ni = 0; ni < 6; ++ni) {
        int j = ni * 16 + (l & 15);
        p[ni] = (i < 92 && j < 92) ? __expf(s[ni] - m) : 0.f;
        sum += p[ni];
      }
      #pragma unroll
      for (int mm = 1; mm < 16; mm <<= 1) sum += __shfl_xor(sum, mm);
      float rs = (i < 92) ? (1.0f / sum) : 0.f;
      #pragma unroll
      for (int ni = 0; ni < 6; ++ni) attv[r][ni] = p[ni] * rs;
    }
    #pragma unroll
    for (int r = 0; r < 4; ++r) {
      int i = 16 * w + (l >> 4) * 4 + r;
      #pragma unroll
      for (int ni = 0; ni < 6; ++ni)
        e0a[i * 104 + ni * 16 + (l & 15)] = (_Float16)attv[r][ni];
    }
  }
  BAR_LGKM();   // att visible

  // ---- PV: out = att @ Wh + bias ; wave w: 2 passes of 32 f-cols
  #pragma unroll 1
  for (int pp = 0; pp < 2; ++pp) {
    int f0 = pp * 256 + w * 32;
    half8 bfp[3][2];
    #pragma unroll
    for (int ks = 0; ks < 3; ++ks)
      #pragma unroll
      for (int ni = 0; ni < 2; ++ni)
        bfp[ks][ni] = *(const half8*)((const char*)whT +
            (f0 + ni * 16 + (l & 15)) * 208 + ks * 64 + (l >> 4) * 16);
    f32x4 pz = {0.f, 0.f, 0.f, 0.f};
    f32x4 pacc[6][2];
    #pragma unroll
    for (int mi = 0; mi < 6; ++mi)
      #pragma unroll
      for (int ni = 0; ni < 2; ++ni) pacc[mi][ni] = pz;
    #pragma unroll
    for (int ks = 0; ks < 3; ++ks) {
      half8 af[6];
      #pragma unroll
      for (int mi = 0; mi < 6; ++mi)
        af[mi] = *(const half8*)((const char*)e0a +
                 (16 * mi + (l & 15)) * 208 + ks * 64 + (l >> 4) * 16);
      #pragma unroll
      for (int mi = 0; mi < 6; ++mi)
        #pragma unroll
        for (int ni = 0; ni < 2; ++ni)
          pacc[mi][ni] = __builtin_amdgcn_mfma_f32_16x16x32_f16(
              af[mi], bfp[ks][ni], pacc[mi][ni], 0, 0, 0);
    }
    #pragma unroll
    for (int ni = 0; ni < 2; ++ni) {
      int fcol = f0 + ni * 16 + (l & 15);
      float bv = bvp[pp][ni];
      #pragma unroll
      for (int mi = 0; mi < 6; ++mi)
        #pragma unroll
        for (int r = 0; r < 4; ++r) {
          int i = 16 * mi + (l >> 4) * 4 + r;
          if (i < 92)
            out[((size_t)b * NNODE + i) * FOUT + fcol] = pacc[mi][ni][r] + bv;
        }
    }
  }
}

// ---------------------------------------------------------------------------
extern "C" void kernel_launch(void* const* d_in, const int* in_sizes, int n_in,
                              void* d_out, int out_size, void* d_ws, size_t ws_size,
                              hipStream_t stream) {
  (void)in_sizes; (void)n_in; (void)out_size; (void)ws_size;
  const float* X    = (const float*)d_in[0];
  const int*   adj  = (const int*)d_in[1];
  const float* W    = (const float*)d_in[2];
  const float* av   = (const float*)d_in[3];
  const float* Am   = (const float*)d_in[4];
  const float* bias = (const float*)d_in[5];
  float* out = (float*)d_out;
  char* ws = (char*)d_ws;

  _Float16* WT  = (_Float16*)(ws);              // 1,048,576 B
  _Float16* ATp = (_Float16*)(ws + 1048576);    //    19,968 B

  prep_kernel<<<68, 256, 0, stream>>>(W, Am, WT, ATp);
  hipFuncSetAttribute((const void*)fused_kernel,
                      hipFuncAttributeMaxDynamicSharedMemorySize, 157952);
  fused_kernel<<<1024, 512, 157952, stream>>>(X, WT, ATp, adj, av, bias, out);
}